// Round 1
// baseline (2893.838 us; speedup 1.0000x reference)
//
#include <hip/hip_runtime.h>

#define NN 50000
#define NE 800000
// D = 128 features, HEADS=8, HID=16

// ---------------- zero workspace ----------------
__global__ __launch_bounds__(256) void zero_kernel(float4* __restrict__ p, int n4) {
    int i = blockIdx.x * 256 + threadIdx.x;
    if (i < n4) p[i] = make_float4(0.f, 0.f, 0.f, 0.f);
}

// ---------------- GEMM: Y[nrows,128] = X[nrows,128] @ W[128,128] + bias ----------------
// block = 256 threads (4 waves). Block covers 64 rows; each wave 16 rows.
// Lane owns cols {lane, lane+64}. W staged in LDS in 32-k chunks; X rows staged once.
__global__ __launch_bounds__(256) void gemm128_kernel(
    const float* __restrict__ X, const float* __restrict__ W,
    const float* __restrict__ bias, float* __restrict__ Y, int nrows)
{
    __shared__ float wl[32 * 128];    // 16 KB
    __shared__ float hl[64 * 132];    // 33.8 KB (pad 128->132 to dodge bank conflicts)
    const int t = threadIdx.x;
    const int lane = t & 63;
    const int wv = t >> 6;
    const int row0 = blockIdx.x * 64;

    // stage 64 rows of X (2048 float4, 8 per thread), coalesced
    {
        const float4* X4 = (const float4*)X;
        #pragma unroll
        for (int i = 0; i < 8; i++) {
            int idx = t + i * 256;
            int rr = idx >> 5, kk = idx & 31;
            int row = row0 + rr;
            float4 v = make_float4(0.f, 0.f, 0.f, 0.f);
            if (row < nrows) v = X4[(long)row * 32 + kk];
            *(float4*)&hl[rr * 132 + kk * 4] = v;
        }
    }

    float acc0[16], acc1[16];
    #pragma unroll
    for (int r = 0; r < 16; r++) { acc0[r] = 0.f; acc1[r] = 0.f; }

    for (int k0 = 0; k0 < 128; k0 += 32) {
        __syncthreads();   // h staged / previous chunk consumed
        {
            const float4* W4 = (const float4*)(W + k0 * 128);
            float4* wl4 = (float4*)wl;
            #pragma unroll
            for (int i = 0; i < 4; i++) wl4[t + i * 256] = W4[t + i * 256];
        }
        __syncthreads();
        #pragma unroll
        for (int kg = 0; kg < 8; kg++) {
            const int k = kg * 4;
            float w0[4], w1[4];
            #pragma unroll
            for (int j = 0; j < 4; j++) {
                w0[j] = wl[(k + j) * 128 + lane];        // stride-1 across lanes: conflict-free
                w1[j] = wl[(k + j) * 128 + lane + 64];
            }
            const int rbase = wv * 16;
            #pragma unroll
            for (int r = 0; r < 16; r++) {
                float4 hv = *(const float4*)&hl[(rbase + r) * 132 + k0 + k];  // wave-broadcast
                acc0[r] = fmaf(hv.x, w0[0], acc0[r]);
                acc0[r] = fmaf(hv.y, w0[1], acc0[r]);
                acc0[r] = fmaf(hv.z, w0[2], acc0[r]);
                acc0[r] = fmaf(hv.w, w0[3], acc0[r]);
                acc1[r] = fmaf(hv.x, w1[0], acc1[r]);
                acc1[r] = fmaf(hv.y, w1[1], acc1[r]);
                acc1[r] = fmaf(hv.z, w1[2], acc1[r]);
                acc1[r] = fmaf(hv.w, w1[3], acc1[r]);
            }
        }
    }

    const float b0 = bias[lane], b1 = bias[lane + 64];
    #pragma unroll
    for (int r = 0; r < 16; r++) {
        int row = row0 + wv * 16 + r;
        if (row < nrows) {
            Y[(long)row * 128 + lane]      = acc0[r] + b0;
            Y[(long)row * 128 + lane + 64] = acc1[r] + b1;
        }
    }
}

// ---------------- edge scatter: agg[dst] += feat[src] * norm[src] ----------------
// 32 threads per edge, float4 per thread, 4 fp32 HW atomics each.
__global__ __launch_bounds__(256) void edge_scatter_kernel(
    const float* __restrict__ feat, const int* __restrict__ src,
    const int* __restrict__ dst, const float* __restrict__ norm,
    float* __restrict__ agg)
{
    int gid = blockIdx.x * 256 + threadIdx.x;
    int e = gid >> 5;
    int q = gid & 31;
    if (e >= NE) return;
    int s = src[e];
    int d = dst[e];
    float nv = norm[s];
    float4 v = ((const float4*)feat)[(long)s * 32 + q];
    float* base = agg + (long)d * 128 + q * 4;
    unsafeAtomicAdd(base + 0, v.x * nv);
    unsafeAtomicAdd(base + 1, v.y * nv);
    unsafeAtomicAdd(base + 2, v.z * nv);
    unsafeAtomicAdd(base + 3, v.w * nv);
}

// ---------------- attention combine (works in flat "reshape" space) ----------------
// m = head*50000 + n2 owns flat chunk [m*16, m*16+16); node n = m/8; head = m/50000.
// Quad of threads per m (thread j handles float4 j). Result written in-place into agg1.
__global__ __launch_bounds__(256) void attention_kernel(
    const float* __restrict__ hf, float* __restrict__ agg1,
    const float* __restrict__ agg2, const float* __restrict__ norm1,
    const float* __restrict__ norm2, const float* __restrict__ al,
    const float* __restrict__ ar)
{
    int gid = blockIdx.x * 256 + threadIdx.x;   // = m*4 + j
    int m = gid >> 2;
    int j = gid & 3;
    if (m >= 8 * NN) return;
    int n = m >> 3;
    int head = m / NN;
    float n1 = norm1[n], n2v = norm2[n];
    float4 f  = ((const float4*)hf)[gid];
    float4 g1 = ((const float4*)agg1)[gid];
    float4 g2 = ((const float4*)agg2)[gid];
    g1.x *= n1; g1.y *= n1; g1.z *= n1; g1.w *= n1;    // h1 = agg1 * norm1[dst-node]
    g2.x *= n2v; g2.y *= n2v; g2.z *= n2v; g2.w *= n2v;
    float4 av = ((const float4*)al)[head * 4 + j];
    float4 rv = ((const float4*)ar)[head * 4 + j];
    float s_ai = f.x * av.x + f.y * av.y + f.z * av.z + f.w * av.w;
    float s1 = g1.x * rv.x + g1.y * rv.y + g1.z * rv.z + g1.w * rv.w;
    float s2 = g2.x * rv.x + g2.y * rv.y + g2.z * rv.z + g2.w * rv.w;
    // reduce across the quad (lanes aligned to 4)
    s_ai += __shfl_xor(s_ai, 1); s_ai += __shfl_xor(s_ai, 2);
    s1   += __shfl_xor(s1, 1);   s1   += __shfl_xor(s1, 2);
    s2   += __shfl_xor(s2, 1);   s2   += __shfl_xor(s2, 2);
    float x1 = s_ai + s1; x1 = x1 > 0.f ? x1 : 0.2f * x1;
    float x2 = s_ai + s2; x2 = x2 > 0.f ? x2 : 0.2f * x2;
    float e1 = fminf(expf(x1), 10.f);   // clip(exp, -10, 10) == min(exp, 10)
    float e2 = fminf(expf(x2), 10.f);
    float inv = 1.f / (e1 + e2);
    float w1 = e1 * inv, w2 = e2 * inv;
    float4 o;
    o.x = w1 * g1.x + w2 * g2.x;
    o.y = w1 * g1.y + w2 * g2.y;
    o.z = w1 * g1.z + w2 * g2.z;
    o.w = w1 * g1.w + w2 * g2.w;
    ((float4*)agg1)[gid] = o;   // each gid slot exclusively owned: safe in-place
}

extern "C" void kernel_launch(void* const* d_in, const int* in_sizes, int n_in,
                              void* d_out, int out_size, void* d_ws, size_t ws_size,
                              hipStream_t stream)
{
    const float* h     = (const float*)d_in[0];
    const int*   src1  = (const int*)  d_in[1];
    const int*   dst1  = (const int*)  d_in[2];
    const int*   src2  = (const int*)  d_in[3];
    const int*   dst2  = (const int*)  d_in[4];
    const float* norm1 = (const float*)d_in[5];
    const float* norm2 = (const float*)d_in[6];
    const float* W_lin = (const float*)d_in[7];
    const float* b_lin = (const float*)d_in[8];
    const float* al    = (const float*)d_in[9];
    const float* ar    = (const float*)d_in[10];
    const float* W_fc  = (const float*)d_in[11];
    const float* b_fc  = (const float*)d_in[12];
    float* out = (float*)d_out;

    float* hf   = (float*)d_ws;                       // 25.6 MB
    float* agg1 = hf   + (size_t)NN * 128;            // 25.6 MB
    float* agg2 = agg1 + (size_t)NN * 128;            // 25.6 MB

    // zero the two accumulators (ws is poisoned 0xAA before every call)
    {
        int n4 = NN * 128 * 2 / 4;   // 3.2M float4
        zero_kernel<<<(n4 + 255) / 256, 256, 0, stream>>>((float4*)agg1, n4);
    }

    gemm128_kernel<<<(NN + 63) / 64, 256, 0, stream>>>(h, W_lin, b_lin, hf, NN);

    edge_scatter_kernel<<<NE * 32 / 256, 256, 0, stream>>>(hf, src1, dst1, norm1, agg1);
    edge_scatter_kernel<<<NE * 32 / 256, 256, 0, stream>>>(hf, src2, dst2, norm2, agg2);

    attention_kernel<<<8 * NN * 4 / 256, 256, 0, stream>>>(hf, agg1, agg2, norm1, norm2, al, ar);

    gemm128_kernel<<<(NN + 63) / 64, 256, 0, stream>>>(agg1, W_fc, b_fc, out, NN);
}

// Round 2
// 548.981 us; speedup vs baseline: 5.2713x; 5.2713x over previous
//
#include <hip/hip_runtime.h>

#define NN 50000
#define NE 800000
// D = 128 features, HEADS=8, HID=16

// ---------------- zero int buffer ----------------
__global__ __launch_bounds__(256) void zero_int_kernel(int* __restrict__ p, int n) {
    int i = blockIdx.x * 256 + threadIdx.x;
    if (i < n) p[i] = 0;
}

// ---------------- GEMM: Y[nrows,128] = X[nrows,128] @ W[128,128] + bias ----------------
__global__ __launch_bounds__(256) void gemm128_kernel(
    const float* __restrict__ X, const float* __restrict__ W,
    const float* __restrict__ bias, float* __restrict__ Y, int nrows)
{
    __shared__ float wl[32 * 128];    // 16 KB
    __shared__ float hl[64 * 132];    // 33.8 KB (pad 128->132 to dodge bank conflicts)
    const int t = threadIdx.x;
    const int lane = t & 63;
    const int wv = t >> 6;
    const int row0 = blockIdx.x * 64;

    // stage 64 rows of X (2048 float4, 8 per thread), coalesced
    {
        const float4* X4 = (const float4*)X;
        #pragma unroll
        for (int i = 0; i < 8; i++) {
            int idx = t + i * 256;
            int rr = idx >> 5, kk = idx & 31;
            int row = row0 + rr;
            float4 v = make_float4(0.f, 0.f, 0.f, 0.f);
            if (row < nrows) v = X4[(long)row * 32 + kk];
            *(float4*)&hl[rr * 132 + kk * 4] = v;
        }
    }

    float acc0[16], acc1[16];
    #pragma unroll
    for (int r = 0; r < 16; r++) { acc0[r] = 0.f; acc1[r] = 0.f; }

    for (int k0 = 0; k0 < 128; k0 += 32) {
        __syncthreads();
        {
            const float4* W4 = (const float4*)(W + k0 * 128);
            float4* wl4 = (float4*)wl;
            #pragma unroll
            for (int i = 0; i < 4; i++) wl4[t + i * 256] = W4[t + i * 256];
        }
        __syncthreads();
        #pragma unroll
        for (int kg = 0; kg < 8; kg++) {
            const int k = kg * 4;
            float w0[4], w1[4];
            #pragma unroll
            for (int j = 0; j < 4; j++) {
                w0[j] = wl[(k + j) * 128 + lane];
                w1[j] = wl[(k + j) * 128 + lane + 64];
            }
            const int rbase = wv * 16;
            #pragma unroll
            for (int r = 0; r < 16; r++) {
                float4 hv = *(const float4*)&hl[(rbase + r) * 132 + k0 + k];
                acc0[r] = fmaf(hv.x, w0[0], acc0[r]);
                acc0[r] = fmaf(hv.y, w0[1], acc0[r]);
                acc0[r] = fmaf(hv.z, w0[2], acc0[r]);
                acc0[r] = fmaf(hv.w, w0[3], acc0[r]);
                acc1[r] = fmaf(hv.x, w1[0], acc1[r]);
                acc1[r] = fmaf(hv.y, w1[1], acc1[r]);
                acc1[r] = fmaf(hv.z, w1[2], acc1[r]);
                acc1[r] = fmaf(hv.w, w1[3], acc1[r]);
            }
        }
    }

    const float b0 = bias[lane], b1 = bias[lane + 64];
    #pragma unroll
    for (int r = 0; r < 16; r++) {
        int row = row0 + wv * 16 + r;
        if (row < nrows) {
            Y[(long)row * 128 + lane]      = acc0[r] + b0;
            Y[(long)row * 128 + lane + 64] = acc1[r] + b1;
        }
    }
}

// ---------------- CSR build: histogram over dst ----------------
__global__ __launch_bounds__(256) void hist_kernel(
    const int* __restrict__ dst1, const int* __restrict__ dst2,
    int* __restrict__ deg1, int* __restrict__ deg2)
{
    int e = blockIdx.x * 256 + threadIdx.x;
    if (e >= NE) return;
    atomicAdd(&deg1[dst1[e]], 1);
    atomicAdd(&deg2[dst2[e]], 1);
}

// ---------------- CSR build: exclusive scan (one workgroup per graph) ----------------
__global__ __launch_bounds__(1024) void scan_kernel(
    const int* __restrict__ degA, int* __restrict__ startA, int* __restrict__ curA,
    const int* __restrict__ degB, int* __restrict__ startB, int* __restrict__ curB)
{
    const int* deg = blockIdx.x ? degB : degA;
    int* start     = blockIdx.x ? startB : startA;
    int* cur       = blockIdx.x ? curB : curA;
    __shared__ int wsum[16];
    const int t = threadIdx.x, lane = t & 63, wv = t >> 6;
    int running = 0;
    for (int base = 0; base < NN; base += 1024) {
        int idx = base + t;
        int v = (idx < NN) ? deg[idx] : 0;
        int orig = v;
        // inclusive wave scan (64 lanes)
        #pragma unroll
        for (int off = 1; off < 64; off <<= 1) {
            int x = __shfl_up(v, off);
            if (lane >= off) v += x;
        }
        if (lane == 63) wsum[wv] = v;
        __syncthreads();
        if (wv == 0) {
            int wval = (lane < 16) ? wsum[lane] : 0;
            #pragma unroll
            for (int off = 1; off < 16; off <<= 1) {
                int x = __shfl_up(wval, off);
                if (lane >= off) wval += x;
            }
            if (lane < 16) wsum[lane] = wval;   // inclusive wave sums
        }
        __syncthreads();
        int woff = (wv == 0) ? 0 : wsum[wv - 1];
        int excl = v - orig + woff + running;
        if (idx < NN) { start[idx] = excl; cur[idx] = excl; }
        int total = wsum[15];
        __syncthreads();   // protect wsum before next chunk
        running += total;
    }
}

// ---------------- CSR build: fill buckets with src ids ----------------
__global__ __launch_bounds__(256) void fill_kernel(
    const int* __restrict__ src1, const int* __restrict__ dst1,
    int* __restrict__ cur1, int* __restrict__ csr1,
    const int* __restrict__ src2, const int* __restrict__ dst2,
    int* __restrict__ cur2, int* __restrict__ csr2)
{
    int e = blockIdx.x * 256 + threadIdx.x;
    if (e >= NE) return;
    int s1 = src1[e], d1 = dst1[e];
    int slot1 = atomicAdd(&cur1[d1], 1);
    csr1[slot1] = s1;
    int s2 = src2[e], d2 = dst2[e];
    int slot2 = atomicAdd(&cur2[d2], 1);
    csr2[slot2] = s2;
}

// ---------------- gather: agg[v] = sum_{e: dst=v} hf[src_e] * norm[src_e] ----------------
// one wave per dst node; lane owns float2 column pair (64*8B = full 512B row, coalesced)
__global__ __launch_bounds__(256) void gather_kernel(
    const float* __restrict__ hf, const int* __restrict__ csr,
    const int* __restrict__ start, const int* __restrict__ deg,
    const float* __restrict__ norm, float* __restrict__ agg)
{
    int wave = (blockIdx.x * 256 + threadIdx.x) >> 6;   // node id
    int lane = threadIdx.x & 63;
    if (wave >= NN) return;
    int st = start[wave];
    int dg = deg[wave];
    const float2* hf2 = (const float2*)hf;
    float2 acc = make_float2(0.f, 0.f);
    int i = 0;
    for (; i + 4 <= dg; i += 4) {
        int s0 = csr[st + i], s1 = csr[st + i + 1], s2 = csr[st + i + 2], s3 = csr[st + i + 3];
        float n0 = norm[s0], n1 = norm[s1], n2 = norm[s2], n3 = norm[s3];
        float2 v0 = hf2[(long)s0 * 64 + lane];
        float2 v1 = hf2[(long)s1 * 64 + lane];
        float2 v2 = hf2[(long)s2 * 64 + lane];
        float2 v3 = hf2[(long)s3 * 64 + lane];
        acc.x = fmaf(v0.x, n0, acc.x); acc.y = fmaf(v0.y, n0, acc.y);
        acc.x = fmaf(v1.x, n1, acc.x); acc.y = fmaf(v1.y, n1, acc.y);
        acc.x = fmaf(v2.x, n2, acc.x); acc.y = fmaf(v2.y, n2, acc.y);
        acc.x = fmaf(v3.x, n3, acc.x); acc.y = fmaf(v3.y, n3, acc.y);
    }
    for (; i < dg; i++) {
        int s = csr[st + i];
        float nv = norm[s];
        float2 v = hf2[(long)s * 64 + lane];
        acc.x = fmaf(v.x, nv, acc.x); acc.y = fmaf(v.y, nv, acc.y);
    }
    ((float2*)agg)[(long)wave * 64 + lane] = acc;
}

// ---------------- attention combine (flat "reshape" space), in-place into agg1 ----------------
__global__ __launch_bounds__(256) void attention_kernel(
    const float* __restrict__ hf, float* __restrict__ agg1,
    const float* __restrict__ agg2, const float* __restrict__ norm1,
    const float* __restrict__ norm2, const float* __restrict__ al,
    const float* __restrict__ ar)
{
    int gid = blockIdx.x * 256 + threadIdx.x;   // = m*4 + j
    int m = gid >> 2;
    int j = gid & 3;
    if (m >= 8 * NN) return;
    int n = m >> 3;
    int head = m / NN;
    float n1 = norm1[n], n2v = norm2[n];
    float4 f  = ((const float4*)hf)[gid];
    float4 g1 = ((const float4*)agg1)[gid];
    float4 g2 = ((const float4*)agg2)[gid];
    g1.x *= n1; g1.y *= n1; g1.z *= n1; g1.w *= n1;
    g2.x *= n2v; g2.y *= n2v; g2.z *= n2v; g2.w *= n2v;
    float4 av = ((const float4*)al)[head * 4 + j];
    float4 rv = ((const float4*)ar)[head * 4 + j];
    float s_ai = f.x * av.x + f.y * av.y + f.z * av.z + f.w * av.w;
    float s1 = g1.x * rv.x + g1.y * rv.y + g1.z * rv.z + g1.w * rv.w;
    float s2 = g2.x * rv.x + g2.y * rv.y + g2.z * rv.z + g2.w * rv.w;
    s_ai += __shfl_xor(s_ai, 1); s_ai += __shfl_xor(s_ai, 2);
    s1   += __shfl_xor(s1, 1);   s1   += __shfl_xor(s1, 2);
    s2   += __shfl_xor(s2, 1);   s2   += __shfl_xor(s2, 2);
    float x1 = s_ai + s1; x1 = x1 > 0.f ? x1 : 0.2f * x1;
    float x2 = s_ai + s2; x2 = x2 > 0.f ? x2 : 0.2f * x2;
    float e1 = fminf(expf(x1), 10.f);
    float e2 = fminf(expf(x2), 10.f);
    float inv = 1.f / (e1 + e2);
    float w1 = e1 * inv, w2 = e2 * inv;
    float4 o;
    o.x = w1 * g1.x + w2 * g2.x;
    o.y = w1 * g1.y + w2 * g2.y;
    o.z = w1 * g1.z + w2 * g2.z;
    o.w = w1 * g1.w + w2 * g2.w;
    ((float4*)agg1)[gid] = o;
}

extern "C" void kernel_launch(void* const* d_in, const int* in_sizes, int n_in,
                              void* d_out, int out_size, void* d_ws, size_t ws_size,
                              hipStream_t stream)
{
    const float* h     = (const float*)d_in[0];
    const int*   src1  = (const int*)  d_in[1];
    const int*   dst1  = (const int*)  d_in[2];
    const int*   src2  = (const int*)  d_in[3];
    const int*   dst2  = (const int*)  d_in[4];
    const float* norm1 = (const float*)d_in[5];
    const float* norm2 = (const float*)d_in[6];
    const float* W_lin = (const float*)d_in[7];
    const float* b_lin = (const float*)d_in[8];
    const float* al    = (const float*)d_in[9];
    const float* ar    = (const float*)d_in[10];
    const float* W_fc  = (const float*)d_in[11];
    const float* b_fc  = (const float*)d_in[12];
    float* out = (float*)d_out;

    // workspace layout
    float* hf    = (float*)d_ws;                          // 25.6 MB
    float* agg1  = hf   + (size_t)NN * 128;               // 25.6 MB
    float* agg2  = agg1 + (size_t)NN * 128;               // 25.6 MB
    int*   csr1  = (int*)(agg2 + (size_t)NN * 128);       // 3.2 MB
    int*   csr2  = csr1 + NE;                             // 3.2 MB
    int*   deg1  = csr2 + NE;                             // 200 KB (deg1,deg2 contiguous)
    int*   deg2  = deg1 + NN;
    int*   start1 = deg2 + NN;
    int*   start2 = start1 + NN;
    int*   cur1   = start2 + NN;
    int*   cur2   = cur1 + NN;

    // zero the two degree histograms (contiguous 2*NN ints)
    zero_int_kernel<<<(2 * NN + 255) / 256, 256, 0, stream>>>(deg1, 2 * NN);

    // hf = h @ W_lin + b_lin
    gemm128_kernel<<<(NN + 63) / 64, 256, 0, stream>>>(h, W_lin, b_lin, hf, NN);

    // build CSR (counting sort by dst) for both graphs
    hist_kernel<<<(NE + 255) / 256, 256, 0, stream>>>(dst1, dst2, deg1, deg2);
    scan_kernel<<<2, 1024, 0, stream>>>(deg1, start1, cur1, deg2, start2, cur2);
    fill_kernel<<<(NE + 255) / 256, 256, 0, stream>>>(src1, dst1, cur1, csr1,
                                                      src2, dst2, cur2, csr2);

    // atomic-free gather per graph
    gather_kernel<<<(NN * 64 + 255) / 256, 256, 0, stream>>>(hf, csr1, start1, deg1, norm1, agg1);
    gather_kernel<<<(NN * 64 + 255) / 256, 256, 0, stream>>>(hf, csr2, start2, deg2, norm2, agg2);

    // attention combine (in-place into agg1)
    attention_kernel<<<8 * NN * 4 / 256, 256, 0, stream>>>(hf, agg1, agg2, norm1, norm2, al, ar);

    // out = agg1 @ W_fc + b_fc
    gemm128_kernel<<<(NN + 63) / 64, 256, 0, stream>>>(agg1, W_fc, b_fc, out, NN);
}